// Round 4
// baseline (1417.921 us; speedup 1.0000x reference)
//
#include <hip/hip_runtime.h>
#include <stdint.h>

// VQVAE quantise — FP32 inputs/outputs (per the reference's declared dtypes),
// distances accumulated in FP64 for argmin robustness.
// x: [256, 8192] f32, dict: [64, 4096, 128] f32
// out: cw_embed [256*8192] f32, then one_hot [256*64*4096] f32.
// ws: idx int32 [256*64].

#define B_SZ 256
#define C_SZ 64
#define E_SZ 128
#define S_SZ 4096
#define CW   8192

typedef __attribute__((ext_vector_type(4))) float  float4a;
typedef __attribute__((ext_vector_type(2))) double double2a;

// grid 1024 = (btile 0..15) x (c 0..63), block 256 (4 waves).
// Thread t handles codes s = s0 + t (s0 = 0,256,...), all 16 b-rows.
__global__ __launch_bounds__(256) void argmin_f64(
    const float* __restrict__ x,
    const float* __restrict__ dict,
    int* __restrict__ idx_out,
    float* __restrict__ cw_out)
{
    __shared__ __align__(16) double xs[16 * E_SZ];   // 16 KB: x rows as f64
    __shared__ double xsq[16];                       // |x|^2 per row (f64)
    __shared__ double rvw[16 * 4];                   // per-wave best val
    __shared__ int    riw[16 * 4];                   // per-wave best idx
    __shared__ int    fid[16];

    const int tid   = threadIdx.x;
    const int lane  = tid & 63;
    const int wid   = tid >> 6;
    const int c     = blockIdx.x & 63;
    const int btile = blockIdx.x >> 6;

    // stage x rows (f32 -> f64)
    {
        int row = tid >> 4;
        int e0  = (tid & 15) * 8;
        const float* xp = x + (size_t)(btile * 16 + row) * CW + c * E_SZ + e0;
        #pragma unroll
        for (int j = 0; j < 8; ++j) xs[row * E_SZ + e0 + j] = (double)xp[j];
    }
    __syncthreads();

    if (tid < 16) {
        double a = 0.0;
        for (int e = 0; e < E_SZ; ++e) { double t = xs[tid * E_SZ + e]; a = fma(t, t, a); }
        xsq[tid] = a;
    }
    __syncthreads();

    double best[16];
    int    bidx[16];
    #pragma unroll
    for (int b = 0; b < 16; ++b) { best[b] = 1.0e300; bidx[b] = 0x7fffffff; }

    for (int s0 = 0; s0 < S_SZ; s0 += 256) {
        int s = s0 + tid;
        const float* drow = dict + (size_t)(c * S_SZ + s) * E_SZ;

        double dsq = 0.0;
        double cross[16];
        #pragma unroll
        for (int b = 0; b < 16; ++b) cross[b] = 0.0;

        for (int ch = 0; ch < 16; ++ch) {
            float4a f0 = *reinterpret_cast<const float4a*>(drow + ch * 8);
            float4a f1 = *reinterpret_cast<const float4a*>(drow + ch * 8 + 4);
            double dd[8];
            #pragma unroll
            for (int j = 0; j < 4; ++j) { dd[j] = (double)f0[j]; dd[4 + j] = (double)f1[j]; }
            #pragma unroll
            for (int j = 0; j < 8; ++j) dsq = fma(dd[j], dd[j], dsq);
            #pragma unroll
            for (int b = 0; b < 16; ++b) {
                const double2a* xr = reinterpret_cast<const double2a*>(&xs[b * E_SZ + ch * 8]);
                #pragma unroll
                for (int p = 0; p < 4; ++p) {
                    double2a xv = xr[p];
                    cross[b] = fma(dd[2 * p],     xv[0], cross[b]);
                    cross[b] = fma(dd[2 * p + 1], xv[1], cross[b]);
                }
            }
        }

        #pragma unroll
        for (int b = 0; b < 16; ++b) {
            double t    = xsq[b] + dsq;                // np op order: (x_sq + d_sq) ...
            double dist = t - 2.0 * cross[b];          // ... - 2*cross
            if (dist < best[b] || (dist == best[b] && s < bidx[b])) {
                best[b] = dist; bidx[b] = s;
            }
        }
    }

    // wave-level lexicographic (value, index) min -> exact first-occurrence argmin
    #pragma unroll
    for (int b = 0; b < 16; ++b) {
        double v = best[b]; int i = bidx[b];
        #pragma unroll
        for (int off = 32; off > 0; off >>= 1) {
            double v2 = __shfl_down(v, off, 64);
            int    i2 = __shfl_down(i, off, 64);
            if (v2 < v || (v2 == v && i2 < i)) { v = v2; i = i2; }
        }
        if (lane == 0) { rvw[b * 4 + wid] = v; riw[b * 4 + wid] = i; }
    }
    __syncthreads();

    if (tid < 16) {
        double bv = 1.0e300; int bi = 0x7fffffff;
        #pragma unroll
        for (int w = 0; w < 4; ++w) {
            double v = rvw[tid * 4 + w];
            int    i = riw[tid * 4 + w];
            if (v < bv || (v == bv && i < bi)) { bv = v; bi = i; }
        }
        idx_out[(btile * 16 + tid) * C_SZ + c] = bi;
        fid[tid] = bi;
    }
    __syncthreads();

    // gather cw_embed: 16 rows x 32 float4 chunks
    for (int u = tid; u < 16 * 32; u += 256) {
        int row = u >> 5, chunk = u & 31;
        int bi = fid[row];
        float4a v = *reinterpret_cast<const float4a*>(
            dict + (size_t)(c * S_SZ + bi) * E_SZ + chunk * 4);
        *reinterpret_cast<float4a*>(
            cw_out + (size_t)(btile * 16 + row) * CW + c * E_SZ + chunk * 4) = v;
    }
}

// one_hot fill: zeros + 1.0f at idx, 16B stores
__global__ void onehot_f32(const int* __restrict__ idx,
                           float* __restrict__ oh) {
    int q = blockIdx.x * 256 + threadIdx.x;   // float4 chunk
    int row = q >> 10;                        // 1024 chunks per (b,c) row of 4096
    int sbase = (q & 1023) * 4;
    int target = idx[row];
    float4a v = {0.f, 0.f, 0.f, 0.f};
    unsigned d = (unsigned)(target - sbase);
    if (d < 4u) v[d] = 1.0f;
    *reinterpret_cast<float4a*>(oh + (size_t)q * 4) = v;
}

extern "C" void kernel_launch(void* const* d_in, const int* in_sizes, int n_in,
                              void* d_out, int out_size, void* d_ws, size_t ws_size,
                              hipStream_t stream) {
    const float* x    = (const float*)d_in[0];
    const float* dict = (const float*)d_in[1];
    float* out = (float*)d_out;
    int* idx = (int*)d_ws;

    argmin_f64<<<dim3(1024), dim3(256), 0, stream>>>(x, dict, idx, out);
    onehot_f32<<<dim3((B_SZ * C_SZ * S_SZ / 4) / 256), dim3(256), 0, stream>>>(
        idx, out + (size_t)B_SZ * CW);
}

// Round 6
// 485.182 us; speedup vs baseline: 2.9225x; 2.9225x over previous
//
#include <hip/hip_runtime.h>
#include <stdint.h>

// VQVAE quantise, fp32 in/out.
// K1: f16-split (hi/lo) MFMA distances, LAYOUT-AGNOSTIC via runtime probe
//     MFMAs that derive the true (lane,reg)->(row,col) C/D attribution.
// one_hot: hipMemsetAsync zeros + scatter of 16384 ones.
// ws: idx int32 [256*64].

#define B_SZ 256
#define C_SZ 64
#define E_SZ 128
#define S_SZ 4096
#define CW   8192
#define LDB  136   // LDS B-row stride in f16

typedef __attribute__((ext_vector_type(4))) float    float4a;
typedef __attribute__((ext_vector_type(8))) _Float16 half8;

__device__ __forceinline__ void split8(float4a f0, float4a f1, half8& hi, half8& lo) {
    #pragma unroll
    for (int j = 0; j < 4; ++j) {
        _Float16 h0 = (_Float16)f0[j];
        hi[j]     = h0;
        lo[j]     = (_Float16)(f0[j] - (float)h0);
        _Float16 h1 = (_Float16)f1[j];
        hi[4 + j] = h1;
        lo[4 + j] = (_Float16)(f1[j] - (float)h1);
    }
}

// grid 256 = (btile 0..3) x (c 0..63), block 512 = 8 waves (mhalf x nquad).
__global__ __launch_bounds__(512, 2) void argmin_mfma(
    const float* __restrict__ x,
    const float* __restrict__ dict,
    int* __restrict__ idx_out,
    float* __restrict__ cw_out)
{
    __shared__ __attribute__((aligned(16))) _Float16 bh[128 * LDB];  // 34.8 KB
    __shared__ __attribute__((aligned(16))) _Float16 bl[128 * LDB];  // 34.8 KB
    __shared__ float4a dsqp[128];
    __shared__ int     fid[64];
    // final reduction tables aliased onto staging LDS (used after the loop)
    float* rv = reinterpret_cast<float*>(bh);   // 64*64 floats = 16 KB
    int*   ri = reinterpret_cast<int*>(bl);     // 64*64 ints   = 16 KB

    const int tid   = threadIdx.x;
    const int lane  = tid & 63;
    const int quad  = lane >> 4;
    const int l15   = lane & 15;
    const int wid   = tid >> 6;
    const int mhalf = wid & 1;
    const int nquad = wid >> 1;
    const int c     = blockIdx.x & 63;
    const int btile = blockIdx.x >> 6;

    // ---- runtime layout probes: true (row, col) of each (lane, reg) ----
    int m_attr[4], n_attr[4];
    {
        half8 ones, enc;
        #pragma unroll
        for (int j = 0; j < 8; ++j) { ones[j] = (_Float16)1.0f; enc[j] = (_Float16)(float)l15; }
        float4a z = {0.f, 0.f, 0.f, 0.f};
        float4a pr = __builtin_amdgcn_mfma_f32_16x16x32_f16(enc, ones, z, 0, 0, 0);
        float4a pc = __builtin_amdgcn_mfma_f32_16x16x32_f16(ones, enc, z, 0, 0, 0);
        #pragma unroll
        for (int r = 0; r < 4; ++r) {
            m_attr[r] = (int)(pr[r] * 0.03125f + 0.5f);   // row feeding this element
            n_attr[r] = (int)(pc[r] * 0.03125f + 0.5f);   // col feeding this element
        }
    }

    // ---- A fragments (regs, whole kernel): loader believes A[m=l15][k=kk*32+quad*8+j] ----
    half8 ah[2][4], al[2][4];
    #pragma unroll
    for (int mi = 0; mi < 2; ++mi) {
        int b = btile * 64 + mhalf * 32 + mi * 16 + l15;
        const float* xr = x + (size_t)b * CW + c * E_SZ;
        #pragma unroll
        for (int kk = 0; kk < 4; ++kk) {
            float4a f0 = *reinterpret_cast<const float4a*>(xr + kk * 32 + quad * 8);
            float4a f1 = *reinterpret_cast<const float4a*>(xr + kk * 32 + quad * 8 + 4);
            split8(f0, f1, ah[mi][kk], al[mi][kk]);
        }
    }

    float bestv[8];
    int   besti[8];
    #pragma unroll
    for (int i = 0; i < 8; ++i) { bestv[i] = 3.4e38f; besti[i] = 0; }

    for (int s0 = 0; s0 < S_SZ; s0 += 128) {
        __syncthreads();
        // ---- stage B tile: 128 s x 128 k, f32 -> hi/lo f16 + dsq partials ----
        {
            int srow = tid >> 2;
            int kq   = (tid & 3) * 32;
            const float* dr = dict + ((size_t)c * S_SZ + (s0 + srow)) * E_SZ + kq;
            float dp = 0.f;
            #pragma unroll
            for (int ck = 0; ck < 4; ++ck) {
                float4a f0 = *reinterpret_cast<const float4a*>(dr + ck * 8);
                float4a f1 = *reinterpret_cast<const float4a*>(dr + ck * 8 + 4);
                half8 h, l;
                split8(f0, f1, h, l);
                #pragma unroll
                for (int j = 0; j < 4; ++j) { dp = fmaf(f0[j], f0[j], dp); dp = fmaf(f1[j], f1[j], dp); }
                *reinterpret_cast<half8*>(bh + srow * LDB + kq + ck * 8) = h;
                *reinterpret_cast<half8*>(bl + srow * LDB + kq + ck * 8) = l;
            }
            dsqp[srow][tid & 3] = dp;
        }
        __syncthreads();

        half8 bhf[2][4], blf[2][4];
        #pragma unroll
        for (int ni = 0; ni < 2; ++ni) {
            int sl = nquad * 32 + ni * 16 + l15;   // loader believes col = l15
            #pragma unroll
            for (int kk = 0; kk < 4; ++kk) {
                bhf[ni][kk] = *reinterpret_cast<const half8*>(bh + sl * LDB + kk * 32 + quad * 8);
                blf[ni][kk] = *reinterpret_cast<const half8*>(bl + sl * LDB + kk * 32 + quad * 8);
            }
        }

        float4a acc[2][2] = {{{0.f,0.f,0.f,0.f},{0.f,0.f,0.f,0.f}},
                             {{0.f,0.f,0.f,0.f},{0.f,0.f,0.f,0.f}}};
        #pragma unroll
        for (int kk = 0; kk < 4; ++kk)
            #pragma unroll
            for (int mi = 0; mi < 2; ++mi)
                #pragma unroll
                for (int ni = 0; ni < 2; ++ni) {
                    acc[mi][ni] = __builtin_amdgcn_mfma_f32_16x16x32_f16(
                        ah[mi][kk], bhf[ni][kk], acc[mi][ni], 0, 0, 0);
                    acc[mi][ni] = __builtin_amdgcn_mfma_f32_16x16x32_f16(
                        ah[mi][kk], blf[ni][kk], acc[mi][ni], 0, 0, 0);
                    acc[mi][ni] = __builtin_amdgcn_mfma_f32_16x16x32_f16(
                        al[mi][kk], bhf[ni][kk], acc[mi][ni], 0, 0, 0);
                }

        // ---- epilogue: dist = d_sq - 2*cross (x_sq const per (b,c): argmin-invariant) ----
        #pragma unroll
        for (int ni = 0; ni < 2; ++ni)
            #pragma unroll
            for (int r = 0; r < 4; ++r) {
                int sl = nquad * 32 + ni * 16 + n_attr[r];   // true col attribution
                float4a q4 = dsqp[sl];
                float dsq = (q4[0] + q4[1]) + (q4[2] + q4[3]);
                int sg = s0 + sl;
                #pragma unroll
                for (int mi = 0; mi < 2; ++mi) {
                    float dist = dsq - 2.0f * acc[mi][ni][r];
                    int slot = mi * 4 + r;
                    if (dist < bestv[slot]) { bestv[slot] = dist; besti[slot] = sg; }
                }
            }
    }

    __syncthreads();   // staging LDS reads done; safe to alias rv/ri onto bh/bl

    // ---- dump: bijective 64x64 scatter using true (row,col) attribution ----
    #pragma unroll
    for (int mi = 0; mi < 2; ++mi)
        #pragma unroll
        for (int r = 0; r < 4; ++r) {
            int row = mhalf * 32 + mi * 16 + m_attr[r];
            int col = nquad * 16 + n_attr[r];
            rv[row * 64 + col] = bestv[mi * 4 + r];
            ri[row * 64 + col] = besti[mi * 4 + r];
        }
    __syncthreads();

    if (tid < 64) {
        float bv = 3.4e38f; int bi = 0x7fffffff;
        for (int j = 0; j < 64; ++j) {
            float v = rv[tid * 64 + j];
            int   i = ri[tid * 64 + j];
            if (v < bv || (v == bv && i < bi)) { bv = v; bi = i; }  // first-occurrence tie
        }
        idx_out[(btile * 64 + tid) * C_SZ + c] = bi;
        fid[tid] = bi;
    }
    __syncthreads();

    // ---- gather cw_embed: 64 rows x 32 float4 chunks ----
    for (int u = tid; u < 64 * 32; u += 512) {
        int row = u >> 5, ch = u & 31;
        int bi = fid[row];
        float4a v = *reinterpret_cast<const float4a*>(
            dict + ((size_t)c * S_SZ + bi) * E_SZ + ch * 4);
        *reinterpret_cast<float4a*>(
            cw_out + (size_t)(btile * 64 + row) * CW + c * E_SZ + ch * 4) = v;
    }
}

__global__ void scatter_ones(const int* __restrict__ idx, float* __restrict__ oh) {
    int r = blockIdx.x * 256 + threadIdx.x;
    oh[(size_t)r * S_SZ + idx[r]] = 1.0f;
}

extern "C" void kernel_launch(void* const* d_in, const int* in_sizes, int n_in,
                              void* d_out, int out_size, void* d_ws, size_t ws_size,
                              hipStream_t stream) {
    const float* x    = (const float*)d_in[0];
    const float* dict = (const float*)d_in[1];
    float* out = (float*)d_out;
    int* idx = (int*)d_ws;
    float* oh = out + (size_t)B_SZ * CW;

    hipMemsetAsync(oh, 0, (size_t)B_SZ * C_SZ * S_SZ * sizeof(float), stream);
    argmin_mfma<<<dim3(256), dim3(512), 0, stream>>>(x, dict, idx, out);
    scatter_ones<<<dim3(B_SZ * C_SZ / 256), dim3(256), 0, stream>>>(idx, oh);
}